// Round 5
// baseline (716.801 us; speedup 1.0000x reference)
//
#include <hip/hip_runtime.h>

#define T_TOK 4096
#define E_EXP 32
#define HDIM  2048
#define IDIM  1024
#define TKROW 16384   // T_TOK * 4
#define BM    256
#define MAXT  96      // max row-tiles

typedef __attribute__((ext_vector_type(8))) short   short8;
typedef __attribute__((ext_vector_type(8))) __bf16  bf16x8;
typedef __attribute__((ext_vector_type(4))) float   f32x4;

typedef const __attribute__((address_space(1))) unsigned int* gas_t;
typedef __attribute__((address_space(3))) unsigned int*       las_t;

static __device__ __forceinline__ void gload16(const void* g, void* l) {
    __builtin_amdgcn_global_load_lds((gas_t)(uintptr_t)g, (las_t)(uintptr_t)l, 16, 0, 0);
}

static __device__ __forceinline__ f32x4 mfma16(short8 a, short8 b, f32x4 c) {
    return __builtin_amdgcn_mfma_f32_16x16x32_bf16(
        __builtin_bit_cast(bf16x8, a), __builtin_bit_cast(bf16x8, b), c, 0, 0, 0);
}

static __device__ __forceinline__ unsigned short f2bf(float f) {
    unsigned u = __builtin_bit_cast(unsigned, f);
    unsigned r = (u + 0x7FFFu + ((u >> 16) & 1u)) >> 16;
    return (unsigned short)r;
}
static __device__ __forceinline__ float bf2f(unsigned short u) {
    return __builtin_bit_cast(float, ((unsigned)u) << 16);
}
static __device__ __forceinline__ unsigned cvtpk(float lo, float hi) {
    unsigned r;
    asm("v_cvt_pk_bf16_f32 %0, %1, %2" : "=v"(r) : "v"(lo), "v"(hi));
    return r;
}
// pinned variant: stays AFTER the preceding counted s_waitcnt
static __device__ __forceinline__ unsigned cvtpkp(float lo, float hi) {
    unsigned r;
    asm volatile("v_cvt_pk_bf16_f32 %0, %1, %2" : "=v"(r) : "v"(lo), "v"(hi) : "memory");
    return r;
}

#define FENCE()    asm volatile("" ::: "memory")
#define WAITVM(N)  asm volatile("s_waitcnt vmcnt(" #N ")" ::: "memory")
#define LGKM0()    asm volatile("s_waitcnt lgkmcnt(0)" ::: "memory")
#define BAR()      do { __builtin_amdgcn_s_barrier(); __builtin_amdgcn_sched_barrier(0); } while (0)

// ---------------- gating: logits -> top4 -> softmax ----------------
__global__ __launch_bounds__(256) void gating_kernel(
    const float* __restrict__ x, const float* __restrict__ gw,
    const float* __restrict__ gb, int* __restrict__ topk_idx,
    float* __restrict__ topk_w)
{
    int wave = threadIdx.x >> 6, lane = threadIdx.x & 63;
    int t = blockIdx.x * 4 + wave;
    const float* xr = x + (size_t)t * HDIM;
    float xv[32];
#pragma unroll
    for (int j = 0; j < 32; j++) xv[j] = xr[lane + 64 * j];
    float logits[E_EXP];
#pragma unroll
    for (int e = 0; e < E_EXP; e++) {
        const float* wr = gw + (size_t)e * HDIM;
        float s = 0.f;
#pragma unroll
        for (int j = 0; j < 32; j++) s = fmaf(xv[j], wr[lane + 64 * j], s);
#pragma unroll
        for (int off = 32; off; off >>= 1) s += __shfl_xor(s, off);
        logits[e] = s + gb[e];
    }
    unsigned sel = 0;
    float v[4]; int id[4];
#pragma unroll
    for (int kk = 0; kk < 4; kk++) {
        float best = -3.4e38f; int bi = 0;
#pragma unroll
        for (int e = 0; e < E_EXP; e++) {
            bool ok = ((sel >> e) & 1u) == 0u;
            bool gt = ok && (logits[e] > best);
            best = gt ? logits[e] : best;
            bi   = gt ? e : bi;
        }
        sel |= 1u << bi; v[kk] = best; id[kk] = bi;
    }
    float m0 = v[0];
    float e0 = __expf(v[0] - m0), e1 = __expf(v[1] - m0);
    float e2 = __expf(v[2] - m0), e3 = __expf(v[3] - m0);
    float inv = 1.f / (e0 + e1 + e2 + e3);
    if (lane == 0) {
        int b4 = t * 4;
        topk_idx[b4 + 0] = id[0]; topk_w[b4 + 0] = e0 * inv;
        topk_idx[b4 + 1] = id[1]; topk_w[b4 + 1] = e1 * inv;
        topk_idx[b4 + 2] = id[2]; topk_w[b4 + 2] = e2 * inv;
        topk_idx[b4 + 3] = id[3]; topk_w[b4 + 3] = e3 * inv;
    }
}

// ---------------- small bookkeeping kernels ----------------
__global__ void init_kernel(int* counts, int* fill) {
    if (threadIdx.x < E_EXP) { counts[threadIdx.x] = 0; fill[threadIdx.x] = 0; }
}

__global__ void histo_kernel(const int* __restrict__ idx, int* counts) {
    int i = blockIdx.x * 256 + threadIdx.x;
    atomicAdd(&counts[idx[i]], 1);
}

__global__ void scan_tiles_kernel(const int* counts, int* offsets,
                                  int* tile_e, int* tile_r, int* ntiles) {
    if (threadIdx.x == 0) {
        int acc = 0;
        for (int e = 0; e < E_EXP; e++) { offsets[e] = acc; acc += counts[e]; }
        offsets[E_EXP] = acc;
        int nt = 0;
        for (int e = 0; e < E_EXP; e++) {
            int c = counts[e];
            for (int r = 0; r < c; r += BM) {
                tile_e[nt] = e; tile_r[nt] = offsets[e] + r; nt++;
            }
        }
        ntiles[0] = nt;
    }
}

__global__ void scatter_kernel(const int* __restrict__ idx, const int* __restrict__ offsets,
                               int* fill, int* __restrict__ pos_of, int* __restrict__ row_tok) {
    int i = blockIdx.x * 256 + threadIdx.x;
    int e = idx[i];
    int pos = offsets[e] + atomicAdd(&fill[e], 1);
    pos_of[i] = pos;
    row_tok[pos] = i >> 2;
}

__global__ __launch_bounds__(64) void gather_kernel(
    const float* __restrict__ x, const int* __restrict__ row_tok,
    unsigned short* __restrict__ xt)
{
    int r = blockIdx.x, lane = threadIdx.x;
    const f32x4* src = (const f32x4*)(x + (size_t)row_tok[r] * HDIM);
    unsigned short* dst = xt + (size_t)r * HDIM;
#pragma unroll
    for (int j = 0; j < 8; j++) {
        f32x4 f = src[lane + 64 * j];
        uint2 o;
        o.x = cvtpk(f[0], f[1]);
        o.y = cvtpk(f[2], f[3]);
        *(uint2*)(dst + 4 * (lane + 64 * j)) = o;
    }
}

// =====================================================================
// grouped GEMM 1 (fused SwiGLU). BM=256, BN=64 (gate & up), BK=64.
// 512 thr / 8 waves (4m x 2n), wave tile 64x32 per matrix.
// Counted-vmcnt pipeline: B loads 2 iterations deep, never drained to 0
// in the main loop. A via global_load_lds (pre-swizzled source).
// =====================================================================
__global__ __launch_bounds__(512, 2) void gemm1_kernel(
    const unsigned short* __restrict__ xt, const float* __restrict__ w_gate,
    const float* __restrict__ b_gate, const float* __restrict__ w_up,
    const float* __restrict__ b_up, const int* __restrict__ tile_e,
    const int* __restrict__ tile_r, const int* __restrict__ ntiles,
    const int* __restrict__ offsets, const int* __restrict__ counts,
    unsigned short* __restrict__ act)
{
    int flat = blockIdx.y * 16 + blockIdx.x;           // 96*16 = 1536
    int swz = (flat & 7) * 192 + (flat >> 3);          // bijective XCD swizzle
    int tid = swz >> 4, nb = swz & 15;
    if (tid >= ntiles[0]) return;
    int e = tile_e[tid], row0 = tile_r[tid];
    int cnt_end = offsets[e] + counts[e];
    int n0 = nb * 64;

    __shared__ unsigned short As[2][BM * 64];   // 64 KB
    __shared__ unsigned short Bg[2][64 * 64];   // 16 KB
    __shared__ unsigned short Bu[2][64 * 64];   // 16 KB

    int t = threadIdx.x, lane = t & 63, w = t >> 6;
    int wr = w >> 1, wc = w & 1;
    int lrow = lane & 15, lg8 = (lane >> 4) * 8;

    f32x4 accg[4][2], accu[4][2];
#pragma unroll
    for (int m = 0; m < 4; m++)
#pragma unroll
        for (int n = 0; n < 2; n++) { accg[m][n] = (f32x4)0.f; accu[m][n] = (f32x4)0.f; }

    int arow_l = lane >> 3;
    int achunk = (lane & 7) ^ arow_l;
    int bn4 = (t & 15) * 4, kr2 = (t >> 4) * 2;
    size_t wB = (size_t)e * ((size_t)HDIM * IDIM) + (size_t)kr2 * IDIM + n0 + bn4;

    f32x4 gS0[2], uS0[2], gS1[2], uS1[2];

#define G1_STAGE_A(KT, BUF) do { int k0_ = (KT) * 64; \
    _Pragma("unroll") for (int i_ = 0; i_ < 4; i_++) { \
        int ar_ = row0 + 32 * w + 8 * i_ + arow_l; \
        if (ar_ > TKROW - 1) ar_ = TKROW - 1; \
        gload16(xt + (size_t)ar_ * HDIM + k0_ + achunk * 8, \
                (void*)&As[BUF][(32 * w + 8 * i_) * 64]); \
    } } while (0)

#define G1_LOADB(KT, GV, UV) do { \
    const float* gp_ = w_gate + wB + (size_t)(KT) * (64 * IDIM); \
    const float* up_ = w_up   + wB + (size_t)(KT) * (64 * IDIM); \
    GV[0] = *(const f32x4*)(gp_); GV[1] = *(const f32x4*)(gp_ + IDIM); \
    UV[0] = *(const f32x4*)(up_); UV[1] = *(const f32x4*)(up_ + IDIM); \
    } while (0)

#define G1_WRITEB(GV, UV, BUF) do { \
    _Pragma("unroll") for (int j_ = 0; j_ < 4; j_++) { \
        unsigned vg_ = cvtpkp(GV[0][j_], GV[1][j_]); \
        unsigned vu_ = cvtpkp(UV[0][j_], UV[1][j_]); \
        int r_ = bn4 + j_; int d_ = r_ * 64 + (kr2 ^ ((r_ & 7) << 3)); \
        *(unsigned*)&Bg[BUF][d_] = vg_; *(unsigned*)&Bu[BUF][d_] = vu_; \
    } } while (0)

#define G1_MFMA(BUF) do { \
    __builtin_amdgcn_s_setprio(1); \
    _Pragma("unroll") for (int kk_ = 0; kk_ < 2; kk_++) { \
        short8 af_[4], bg_[2], bu_[2]; \
        int ke_ = kk_ * 32 + lg8; \
        _Pragma("unroll") for (int m_ = 0; m_ < 4; m_++) { \
            int rr_ = wr * 64 + m_ * 16 + lrow; \
            af_[m_] = *(const short8*)&As[BUF][rr_ * 64 + (ke_ ^ ((rr_ & 7) << 3))]; } \
        _Pragma("unroll") for (int n_ = 0; n_ < 2; n_++) { \
            int rr_ = wc * 32 + n_ * 16 + lrow; \
            int d_ = rr_ * 64 + (ke_ ^ ((rr_ & 7) << 3)); \
            bg_[n_] = *(const short8*)&Bg[BUF][d_]; \
            bu_[n_] = *(const short8*)&Bu[BUF][d_]; } \
        _Pragma("unroll") for (int m_ = 0; m_ < 4; m_++) \
        _Pragma("unroll") for (int n_ = 0; n_ < 2; n_++) { \
            accg[m_][n_] = mfma16(af_[m_], bg_[n_], accg[m_][n_]); \
            accu[m_][n_] = mfma16(af_[m_], bu_[n_], accu[m_][n_]); } \
    } \
    __builtin_amdgcn_s_setprio(0); } while (0)

    // prologue: outstanding after = A0:4, B0:4, B1:4
    G1_STAGE_A(0, 0); FENCE();
    G1_LOADB(0, gS0, uS0); FENCE();
    G1_LOADB(1, gS1, uS1); FENCE();
    WAITVM(4);                       // A0 + B0 done; B1 in flight
    G1_WRITEB(gS0, uS0, 0);
    LGKM0(); BAR();

    int cur = 0;
#pragma unroll 1
    for (int kt = 0; kt < 30; kt += 2) {
        // body t=kt (even): S0 <- B(t+2); write S1 = B(t+1)
        FENCE(); G1_STAGE_A(kt + 1, cur ^ 1); FENCE();
        G1_LOADB(kt + 2, gS0, uS0); FENCE();
        G1_MFMA(cur);
        WAITVM(8);                   // B(t+1) ready
        G1_WRITEB(gS1, uS1, cur ^ 1);
        WAITVM(4);                   // A(t+1) staged; B(t+2) stays in flight
        LGKM0(); BAR();
        cur ^= 1;
        // body t=kt+1 (odd): S1 <- B(t+3); write S0 = B(t+2)
        FENCE(); G1_STAGE_A(kt + 2, cur ^ 1); FENCE();
        G1_LOADB(kt + 3, gS1, uS1); FENCE();
        G1_MFMA(cur);
        WAITVM(8);
        G1_WRITEB(gS0, uS0, cur ^ 1);
        WAITVM(4);
        LGKM0(); BAR();
        cur ^= 1;
    }
    // t=30: stage A(31); write S1 = B(31); no new B loads
    FENCE(); G1_STAGE_A(31, cur ^ 1); FENCE();
    G1_MFMA(cur);
    WAITVM(4);
    G1_WRITEB(gS1, uS1, cur ^ 1);
    WAITVM(0);
    LGKM0(); BAR();
    cur ^= 1;
    // t=31
    G1_MFMA(cur);
#undef G1_STAGE_A
#undef G1_LOADB
#undef G1_WRITEB
#undef G1_MFMA

    // epilogue: fused SwiGLU
#pragma unroll
    for (int nf = 0; nf < 2; nf++) {
        int col = n0 + wc * 32 + nf * 16 + lrow;
        float bgv = b_gate[e * IDIM + col];
        float buv = b_up[e * IDIM + col];
#pragma unroll
        for (int m = 0; m < 4; m++) {
            int rb = row0 + wr * 64 + m * 16 + (lane >> 4) * 4;
#pragma unroll
            for (int r = 0; r < 4; r++) {
                int grow = rb + r;
                if (grow < cnt_end) {
                    float gv = accg[m][nf][r] + bgv;
                    float uv = accu[m][nf][r] + buv;
                    gv = fminf(gv, 7.f);
                    uv = fminf(fmaxf(uv, -7.f), 7.f);
                    float glu = gv / (1.f + __expf(-1.702f * gv));
                    act[(size_t)grow * IDIM + col] = f2bf((uv + 1.f) * glu);
                }
            }
        }
    }
}

// =====================================================================
// grouped GEMM 2: outs = act @ w_down + b_down
// BM=256, BN=128, BK=64, 512 thr / 8 waves (4m x 2n), wave tile 64x64.
// Same counted-vmcnt pipeline.
// =====================================================================
__global__ __launch_bounds__(512, 2) void gemm2_kernel(
    const unsigned short* __restrict__ actb, const float* __restrict__ w_down,
    const float* __restrict__ b_down, const int* __restrict__ tile_e,
    const int* __restrict__ tile_r, const int* __restrict__ ntiles,
    const int* __restrict__ offsets, const int* __restrict__ counts,
    unsigned short* __restrict__ outs)
{
    int flat = blockIdx.y * 16 + blockIdx.x;
    int swz = (flat & 7) * 192 + (flat >> 3);
    int tid = swz >> 4, nb = swz & 15;
    if (tid >= ntiles[0]) return;
    int e = tile_e[tid], row0 = tile_r[tid];
    int cnt_end = offsets[e] + counts[e];
    int n0 = nb * 128;

    __shared__ unsigned short As[2][BM * 64];    // 64 KB
    __shared__ unsigned short Bs[2][128 * 64];   // 32 KB

    int t = threadIdx.x, lane = t & 63, w = t >> 6;
    int wr = w >> 1, wc = w & 1;
    int lrow = lane & 15, lg8 = (lane >> 4) * 8;

    f32x4 acc[4][4];
#pragma unroll
    for (int m = 0; m < 4; m++)
#pragma unroll
        for (int n = 0; n < 4; n++) acc[m][n] = (f32x4)0.f;

    int arow_l = lane >> 3;
    int achunk = (lane & 7) ^ arow_l;
    int bn4 = (t & 31) * 4, kr4 = (t >> 5) * 4;
    size_t wB = (size_t)e * ((size_t)IDIM * HDIM) + (size_t)kr4 * HDIM + n0 + bn4;

    f32x4 dS0[4], dS1[4];

#define G2_STAGE_A(KT, BUF) do { int k0_ = (KT) * 64; \
    _Pragma("unroll") for (int i_ = 0; i_ < 4; i_++) { \
        int ar_ = row0 + 32 * w + 8 * i_ + arow_l; \
        if (ar_ > TKROW - 1) ar_ = TKROW - 1; \
        gload16(actb + (size_t)ar_ * IDIM + k0_ + achunk * 8, \
                (void*)&As[BUF][(32 * w + 8 * i_) * 64]); \
    } } while (0)

#define G2_LOADB(KT, DV) do { \
    const float* gp_ = w_down + wB + (size_t)(KT) * (64 * HDIM); \
    DV[0] = *(const f32x4*)(gp_);            DV[1] = *(const f32x4*)(gp_ + HDIM); \
    DV[2] = *(const f32x4*)(gp_ + 2 * HDIM); DV[3] = *(const f32x4*)(gp_ + 3 * HDIM); \
    } while (0)

#define G2_WRITEB(DV, BUF) do { \
    _Pragma("unroll") for (int j_ = 0; j_ < 4; j_++) { \
        uint2 v_; \
        v_.x = cvtpkp(DV[0][j_], DV[1][j_]); v_.y = cvtpkp(DV[2][j_], DV[3][j_]); \
        int r_ = bn4 + j_; int d_ = r_ * 64 + (kr4 ^ ((r_ & 7) << 3)); \
        *(uint2*)&Bs[BUF][d_] = v_; \
    } } while (0)

#define G2_MFMA(BUF) do { \
    __builtin_amdgcn_s_setprio(1); \
    _Pragma("unroll") for (int kk_ = 0; kk_ < 2; kk_++) { \
        short8 af_[4], bf_[4]; \
        int ke_ = kk_ * 32 + lg8; \
        _Pragma("unroll") for (int m_ = 0; m_ < 4; m_++) { \
            int rr_ = wr * 64 + m_ * 16 + lrow; \
            af_[m_] = *(const short8*)&As[BUF][rr_ * 64 + (ke_ ^ ((rr_ & 7) << 3))]; } \
        _Pragma("unroll") for (int n_ = 0; n_ < 4; n_++) { \
            int rr_ = wc * 64 + n_ * 16 + lrow; \
            bf_[n_] = *(const short8*)&Bs[BUF][rr_ * 64 + (ke_ ^ ((rr_ & 7) << 3))]; } \
        _Pragma("unroll") for (int m_ = 0; m_ < 4; m_++) \
        _Pragma("unroll") for (int n_ = 0; n_ < 4; n_++) \
            acc[m_][n_] = mfma16(af_[m_], bf_[n_], acc[m_][n_]); \
    } \
    __builtin_amdgcn_s_setprio(0); } while (0)

    G2_STAGE_A(0, 0); FENCE();
    G2_LOADB(0, dS0); FENCE();
    G2_LOADB(1, dS1); FENCE();
    WAITVM(4);
    G2_WRITEB(dS0, 0);
    LGKM0(); BAR();

    int cur = 0;
#pragma unroll 1
    for (int kt = 0; kt < 14; kt += 2) {
        FENCE(); G2_STAGE_A(kt + 1, cur ^ 1); FENCE();
        G2_LOADB(kt + 2, dS0); FENCE();
        G2_MFMA(cur);
        WAITVM(8);
        G2_WRITEB(dS1, cur ^ 1);
        WAITVM(4);
        LGKM0(); BAR();
        cur ^= 1;
        FENCE(); G2_STAGE_A(kt + 2, cur ^ 1); FENCE();
        G2_LOADB(kt + 3, dS1); FENCE();
        G2_MFMA(cur);
        WAITVM(8);
        G2_WRITEB(dS0, cur ^ 1);
        WAITVM(4);
        LGKM0(); BAR();
        cur ^= 1;
    }
    // t=14
    FENCE(); G2_STAGE_A(15, cur ^ 1); FENCE();
    G2_MFMA(cur);
    WAITVM(4);
    G2_WRITEB(dS1, cur ^ 1);
    WAITVM(0);
    LGKM0(); BAR();
    cur ^= 1;
    // t=15
    G2_MFMA(cur);
#undef G2_STAGE_A
#undef G2_LOADB
#undef G2_WRITEB
#undef G2_MFMA

#pragma unroll
    for (int nf = 0; nf < 4; nf++) {
        int col = n0 + wc * 64 + nf * 16 + lrow;
        float bdv = b_down[e * HDIM + col];
#pragma unroll
        for (int m = 0; m < 4; m++) {
            int rb = row0 + wr * 64 + m * 16 + (lane >> 4) * 4;
#pragma unroll
            for (int r = 0; r < 4; r++) {
                int grow = rb + r;
                if (grow < cnt_end)
                    outs[(size_t)grow * HDIM + col] = f2bf(acc[m][nf][r] + bdv);
            }
        }
    }
}

// ---------------- combine ----------------
__global__ __launch_bounds__(256) void combine_kernel(
    const unsigned short* __restrict__ outs, const int* __restrict__ pos_of,
    const float* __restrict__ topk_w, float* __restrict__ y)
{
    int tok = blockIdx.x;
    int c0 = threadIdx.x * 8;
    float acc[8] = {0.f, 0.f, 0.f, 0.f, 0.f, 0.f, 0.f, 0.f};
#pragma unroll
    for (int k = 0; k < 4; k++) {
        int pos = pos_of[tok * 4 + k];
        float w = topk_w[tok * 4 + k];
        short8 vv = *(const short8*)(outs + (size_t)pos * HDIM + c0);
#pragma unroll
        for (int j = 0; j < 8; j++)
            acc[j] = fmaf(w, bf2f((unsigned short)vv[j]), acc[j]);
    }
    float4 o0 = make_float4(acc[0], acc[1], acc[2], acc[3]);
    float4 o1 = make_float4(acc[4], acc[5], acc[6], acc[7]);
    *(float4*)(y + (size_t)tok * HDIM + c0)     = o0;
    *(float4*)(y + (size_t)tok * HDIM + c0 + 4) = o1;
}

// ---------------- launch ----------------
extern "C" void kernel_launch(void* const* d_in, const int* in_sizes, int n_in,
                              void* d_out, int out_size, void* d_ws, size_t ws_size,
                              hipStream_t stream) {
    const float* x      = (const float*)d_in[0];
    const float* gw     = (const float*)d_in[1];
    const float* gb     = (const float*)d_in[2];
    const float* w_gate = (const float*)d_in[3];
    const float* b_gate = (const float*)d_in[4];
    const float* w_up   = (const float*)d_in[5];
    const float* b_up   = (const float*)d_in[6];
    const float* w_down = (const float*)d_in[7];
    const float* b_down = (const float*)d_in[8];
    float* y = (float*)d_out;

    char* base = (char*)d_ws;
    size_t off = 0;
    int*   topk_idx = (int*)(base + off);   off += (size_t)TKROW * 4;
    float* topk_w   = (float*)(base + off); off += (size_t)TKROW * 4;
    int*   counts   = (int*)(base + off);   off += 256;
    int*   offsets  = (int*)(base + off);   off += 256;
    int*   fill     = (int*)(base + off);   off += 256;
    int*   ntiles   = (int*)(base + off);   off += 256;
    int*   tile_e   = (int*)(base + off);   off += 1024;
    int*   tile_r   = (int*)(base + off);   off += 1024;
    int*   pos_of   = (int*)(base + off);   off += (size_t)TKROW * 4;
    int*   row_tok  = (int*)(base + off);   off += (size_t)TKROW * 4;
    unsigned short* xt   = (unsigned short*)(base + off); off += (size_t)TKROW * HDIM * 2;
    unsigned short* act  = (unsigned short*)(base + off); off += (size_t)TKROW * IDIM * 2;
    unsigned short* outs = (unsigned short*)(base + off); off += (size_t)TKROW * HDIM * 2;

    init_kernel<<<1, 64, 0, stream>>>(counts, fill);
    gating_kernel<<<T_TOK / 4, 256, 0, stream>>>(x, gw, gb, topk_idx, topk_w);
    histo_kernel<<<TKROW / 256, 256, 0, stream>>>(topk_idx, counts);
    scan_tiles_kernel<<<1, 64, 0, stream>>>(counts, offsets, tile_e, tile_r, ntiles);
    scatter_kernel<<<TKROW / 256, 256, 0, stream>>>(topk_idx, offsets, fill, pos_of, row_tok);
    gather_kernel<<<TKROW, 64, 0, stream>>>(x, row_tok, xt);
    gemm1_kernel<<<dim3(16, MAXT), 512, 0, stream>>>(
        xt, w_gate, b_gate, w_up, b_up, tile_e, tile_r, ntiles, offsets, counts, act);
    gemm2_kernel<<<dim3(16, MAXT), 512, 0, stream>>>(
        act, w_down, b_down, tile_e, tile_r, ntiles, offsets, counts, outs);
    combine_kernel<<<T_TOK, 256, 0, stream>>>(outs, pos_of, topk_w, y);
}

// Round 6
// 636.550 us; speedup vs baseline: 1.1261x; 1.1261x over previous
//
#include <hip/hip_runtime.h>

#define T_TOK 4096
#define E_EXP 32
#define HDIM  2048
#define IDIM  1024
#define TKROW 16384   // T_TOK * 4
#define BM    256
#define MAXT  96      // max row-tiles

typedef __attribute__((ext_vector_type(8))) short   short8;
typedef __attribute__((ext_vector_type(8))) __bf16  bf16x8;
typedef __attribute__((ext_vector_type(4))) float   f32x4;

typedef const __attribute__((address_space(1))) unsigned int* gas_t;
typedef __attribute__((address_space(3))) unsigned int*       las_t;

static __device__ __forceinline__ void gload16(const void* g, void* l) {
    __builtin_amdgcn_global_load_lds((gas_t)(uintptr_t)g, (las_t)(uintptr_t)l, 16, 0, 0);
}

static __device__ __forceinline__ f32x4 mfma16(short8 a, short8 b, f32x4 c) {
    return __builtin_amdgcn_mfma_f32_16x16x32_bf16(
        __builtin_bit_cast(bf16x8, a), __builtin_bit_cast(bf16x8, b), c, 0, 0, 0);
}

static __device__ __forceinline__ unsigned short f2bf(float f) {
    unsigned u = __builtin_bit_cast(unsigned, f);
    unsigned r = (u + 0x7FFFu + ((u >> 16) & 1u)) >> 16;
    return (unsigned short)r;
}
static __device__ __forceinline__ float bf2f(unsigned short u) {
    return __builtin_bit_cast(float, ((unsigned)u) << 16);
}
static __device__ __forceinline__ unsigned cvtpk(float lo, float hi) {
    unsigned r;
    asm("v_cvt_pk_bf16_f32 %0, %1, %2" : "=v"(r) : "v"(lo), "v"(hi));
    return r;
}
static __device__ __forceinline__ unsigned cvtpkp(float lo, float hi) {
    unsigned r;
    asm volatile("v_cvt_pk_bf16_f32 %0, %1, %2" : "=v"(r) : "v"(lo), "v"(hi) : "memory");
    return r;
}

#define FENCE()    asm volatile("" ::: "memory")
#define WAITVM(N)  asm volatile("s_waitcnt vmcnt(" #N ")" ::: "memory")
#define LGKM0()    asm volatile("s_waitcnt lgkmcnt(0)" ::: "memory")
#define BAR()      do { __builtin_amdgcn_s_barrier(); __builtin_amdgcn_sched_barrier(0); } while (0)

// ---------------- gating: logits -> top4 -> softmax ----------------
__global__ __launch_bounds__(256) void gating_kernel(
    const float* __restrict__ x, const float* __restrict__ gw,
    const float* __restrict__ gb, int* __restrict__ topk_idx,
    float* __restrict__ topk_w)
{
    int wave = threadIdx.x >> 6, lane = threadIdx.x & 63;
    int t = blockIdx.x * 4 + wave;
    const float* xr = x + (size_t)t * HDIM;
    float xv[32];
#pragma unroll
    for (int j = 0; j < 32; j++) xv[j] = xr[lane + 64 * j];
    float logits[E_EXP];
#pragma unroll
    for (int e = 0; e < E_EXP; e++) {
        const float* wr = gw + (size_t)e * HDIM;
        float s = 0.f;
#pragma unroll
        for (int j = 0; j < 32; j++) s = fmaf(xv[j], wr[lane + 64 * j], s);
#pragma unroll
        for (int off = 32; off; off >>= 1) s += __shfl_xor(s, off);
        logits[e] = s + gb[e];
    }
    unsigned sel = 0;
    float v[4]; int id[4];
#pragma unroll
    for (int kk = 0; kk < 4; kk++) {
        float best = -3.4e38f; int bi = 0;
#pragma unroll
        for (int e = 0; e < E_EXP; e++) {
            bool ok = ((sel >> e) & 1u) == 0u;
            bool gt = ok && (logits[e] > best);
            best = gt ? logits[e] : best;
            bi   = gt ? e : bi;
        }
        sel |= 1u << bi; v[kk] = best; id[kk] = bi;
    }
    float m0 = v[0];
    float e0 = __expf(v[0] - m0), e1 = __expf(v[1] - m0);
    float e2 = __expf(v[2] - m0), e3 = __expf(v[3] - m0);
    float inv = 1.f / (e0 + e1 + e2 + e3);
    if (lane == 0) {
        int b4 = t * 4;
        topk_idx[b4 + 0] = id[0]; topk_w[b4 + 0] = e0 * inv;
        topk_idx[b4 + 1] = id[1]; topk_w[b4 + 1] = e1 * inv;
        topk_idx[b4 + 2] = id[2]; topk_w[b4 + 2] = e2 * inv;
        topk_idx[b4 + 3] = id[3]; topk_w[b4 + 3] = e3 * inv;
    }
}

// ---------------- small bookkeeping kernels ----------------
__global__ void init_kernel(int* counts, int* fill) {
    if (threadIdx.x < E_EXP) { counts[threadIdx.x] = 0; fill[threadIdx.x] = 0; }
}

__global__ void histo_kernel(const int* __restrict__ idx, int* counts) {
    int i = blockIdx.x * 256 + threadIdx.x;
    atomicAdd(&counts[idx[i]], 1);
}

__global__ void scan_tiles_kernel(const int* counts, int* offsets,
                                  int* tile_e, int* tile_r, int* ntiles) {
    if (threadIdx.x == 0) {
        int acc = 0;
        for (int e = 0; e < E_EXP; e++) { offsets[e] = acc; acc += counts[e]; }
        offsets[E_EXP] = acc;
        int nt = 0;
        for (int e = 0; e < E_EXP; e++) {
            int c = counts[e];
            for (int r = 0; r < c; r += BM) {
                tile_e[nt] = e; tile_r[nt] = offsets[e] + r; nt++;
            }
        }
        ntiles[0] = nt;
    }
}

__global__ void scatter_kernel(const int* __restrict__ idx, const int* __restrict__ offsets,
                               int* fill, int* __restrict__ pos_of, int* __restrict__ row_tok) {
    int i = blockIdx.x * 256 + threadIdx.x;
    int e = idx[i];
    int pos = offsets[e] + atomicAdd(&fill[e], 1);
    pos_of[i] = pos;
    row_tok[pos] = i >> 2;
}

__global__ __launch_bounds__(64) void gather_kernel(
    const float* __restrict__ x, const int* __restrict__ row_tok,
    unsigned short* __restrict__ xt)
{
    int r = blockIdx.x, lane = threadIdx.x;
    const f32x4* src = (const f32x4*)(x + (size_t)row_tok[r] * HDIM);
    unsigned short* dst = xt + (size_t)r * HDIM;
#pragma unroll
    for (int j = 0; j < 8; j++) {
        f32x4 f = src[lane + 64 * j];
        uint2 o;
        o.x = cvtpk(f[0], f[1]);
        o.y = cvtpk(f[2], f[3]);
        *(uint2*)(dst + 4 * (lane + 64 * j)) = o;
    }
}

// =====================================================================
// grouped GEMM 1 (fused SwiGLU): BM=256, BN=128 (gate & up), BK=64,
// 512 thr / 8 waves (2m x 4n), wave tile 128x32 per matrix.
// 2-deep counted-vmcnt B pipeline, waits between split MFMA halves.
// =====================================================================
__global__ __launch_bounds__(512, 2) void gemm1_kernel(
    const unsigned short* __restrict__ xt, const float* __restrict__ w_gate,
    const float* __restrict__ b_gate, const float* __restrict__ w_up,
    const float* __restrict__ b_up, const int* __restrict__ tile_e,
    const int* __restrict__ tile_r, const int* __restrict__ ntiles,
    const int* __restrict__ offsets, const int* __restrict__ counts,
    unsigned short* __restrict__ act)
{
    int flat = blockIdx.y * 8 + blockIdx.x;
    int swz = (flat & 7) * (MAXT) + (flat >> 3);
    int tid = swz >> 3, nb = swz & 7;
    if (tid >= ntiles[0]) return;
    int e = tile_e[tid], row0 = tile_r[tid];
    int cnt_end = offsets[e] + counts[e];
    int n0 = nb * 128;

    __shared__ unsigned short As[2][BM * 64];     // 64 KB
    __shared__ unsigned short Bgs[2][128 * 64];   // 32 KB
    __shared__ unsigned short Bus[2][128 * 64];   // 32 KB

    int t = threadIdx.x, lane = t & 63, w = t >> 6;
    int wr = w >> 2, wc = w & 3;
    int lrow = lane & 15, lg8 = (lane >> 4) * 8;

    f32x4 accg[8][2], accu[8][2];
#pragma unroll
    for (int m = 0; m < 8; m++)
#pragma unroll
        for (int n = 0; n < 2; n++) { accg[m][n] = (f32x4)0.f; accu[m][n] = (f32x4)0.f; }

    int arow_l = (lane >> 3);
    int achunk = (lane & 7) ^ arow_l;
    int bn = (t & 31) * 4, bk = (t >> 5) * 4;
    int bfswz = ((t & 31) & 7) << 3;
    size_t wB = (size_t)e * ((size_t)HDIM * IDIM) + (size_t)bk * IDIM + n0 + bn;

    f32x4 gS0[4], uS0[4], gS1[4], uS1[4];

#define G1_STAGE_A(KT, BUF) do { int k0_ = (KT) * 64; \
    _Pragma("unroll") for (int i_ = 0; i_ < 4; i_++) { \
        int ar_ = row0 + 32 * w + 8 * i_ + arow_l; \
        if (ar_ > TKROW - 1) ar_ = TKROW - 1; \
        gload16(xt + (size_t)ar_ * HDIM + k0_ + achunk * 8, \
                (void*)&As[BUF][(32 * w + 8 * i_) * 64]); \
    } } while (0)

#define G1_LOADB(KT, GV, UV) do { \
    const float* gp_ = w_gate + wB + (size_t)(KT) * 64 * IDIM; \
    const float* up_ = w_up   + wB + (size_t)(KT) * 64 * IDIM; \
    _Pragma("unroll") for (int kk_ = 0; kk_ < 4; kk_++) { \
        GV[kk_] = *(const f32x4*)(gp_ + (size_t)kk_ * IDIM); \
        UV[kk_] = *(const f32x4*)(up_ + (size_t)kk_ * IDIM); \
    } } while (0)

#define G1_WRITEB(GV, UV, BUF) do { \
    _Pragma("unroll") for (int j_ = 0; j_ < 4; j_++) { \
        uint2 vg_, vu_; \
        vg_.x = cvtpkp(GV[0][j_], GV[1][j_]); vg_.y = cvtpkp(GV[2][j_], GV[3][j_]); \
        vu_.x = cvtpkp(UV[0][j_], UV[1][j_]); vu_.y = cvtpkp(UV[2][j_], UV[3][j_]); \
        int d_ = (bn + j_) * 64 + (bk ^ bfswz); \
        *(uint2*)&Bgs[BUF][d_] = vg_; *(uint2*)&Bus[BUF][d_] = vu_; \
    } } while (0)

#define G1_MFMA_H(BUF, KK) do { \
    __builtin_amdgcn_s_setprio(1); \
    { \
        short8 af_[8], bg_[2], bu_[2]; \
        int ke_ = (KK) * 32 + lg8; \
        _Pragma("unroll") for (int m_ = 0; m_ < 8; m_++) \
            af_[m_] = *(const short8*)&As[BUF][(wr * 128 + m_ * 16 + lrow) * 64 + (ke_ ^ ((lrow & 7) << 3))]; \
        _Pragma("unroll") for (int n_ = 0; n_ < 2; n_++) { \
            int rb_ = wc * 32 + n_ * 16 + lrow; \
            int d_ = rb_ * 64 + (ke_ ^ (((rb_ >> 2) & 7) << 3)); \
            bg_[n_] = *(const short8*)&Bgs[BUF][d_]; \
            bu_[n_] = *(const short8*)&Bus[BUF][d_]; \
        } \
        _Pragma("unroll") for (int m_ = 0; m_ < 8; m_++) \
        _Pragma("unroll") for (int n_ = 0; n_ < 2; n_++) { \
            accg[m_][n_] = mfma16(af_[m_], bg_[n_], accg[m_][n_]); \
            accu[m_][n_] = mfma16(af_[m_], bu_[n_], accu[m_][n_]); \
        } \
    } \
    __builtin_amdgcn_s_setprio(0); } while (0)

    // prologue: queue = [A0:4, B0:8, B1:8]
    G1_STAGE_A(0, 0); FENCE();
    G1_LOADB(0, gS0, uS0); FENCE();
    G1_LOADB(1, gS1, uS1); FENCE();
    WAITVM(8);                 // A0 + B0 done; B1 in flight
    G1_WRITEB(gS0, uS0, 0);
    LGKM0(); BAR();

    int cur = 0;
#pragma unroll 1
    for (int kt = 0; kt < 30; kt += 2) {
        // even step t=kt: B(t+1) in S1; load B(t+2)->S0
        FENCE(); G1_STAGE_A(kt + 1, cur ^ 1); FENCE();
        G1_LOADB(kt + 2, gS0, uS0); FENCE();
        G1_MFMA_H(cur, 0);
        WAITVM(12);            // B(t+1) regs ready (A(t+1)+B(t+2)=12 left)
        G1_WRITEB(gS1, uS1, cur ^ 1);
        G1_MFMA_H(cur, 1);
        WAITVM(8);             // A(t+1) staged; B(t+2) stays in flight
        LGKM0(); BAR(); cur ^= 1;
        // odd step t=kt+1: B(t+1) in S0; load B(t+2)->S1
        FENCE(); G1_STAGE_A(kt + 2, cur ^ 1); FENCE();
        G1_LOADB(kt + 3, gS1, uS1); FENCE();
        G1_MFMA_H(cur, 0);
        WAITVM(12);
        G1_WRITEB(gS0, uS0, cur ^ 1);
        G1_MFMA_H(cur, 1);
        WAITVM(8);
        LGKM0(); BAR(); cur ^= 1;
    }
    // t=30: B(31) in S1; no new B loads. queue entering: [B31:8]
    FENCE(); G1_STAGE_A(31, cur ^ 1); FENCE();
    G1_MFMA_H(cur, 0);
    WAITVM(4);                 // B31 done; A31 may remain
    G1_WRITEB(gS1, uS1, cur ^ 1);
    G1_MFMA_H(cur, 1);
    WAITVM(0);
    LGKM0(); BAR(); cur ^= 1;
    // t=31
    G1_MFMA_H(cur, 0);
    G1_MFMA_H(cur, 1);
#undef G1_STAGE_A
#undef G1_LOADB
#undef G1_WRITEB
#undef G1_MFMA_H

    // epilogue: fused SwiGLU
#pragma unroll
    for (int nf = 0; nf < 2; nf++) {
        int col = n0 + wc * 32 + nf * 16 + lrow;
        float bgv = b_gate[e * IDIM + col];
        float buv = b_up[e * IDIM + col];
#pragma unroll
        for (int m = 0; m < 8; m++) {
            int rb = row0 + wr * 128 + m * 16 + (lane >> 4) * 4;
#pragma unroll
            for (int r = 0; r < 4; r++) {
                int grow = rb + r;
                if (grow < cnt_end) {
                    float gv = accg[m][nf][r] + bgv;
                    float uv = accu[m][nf][r] + buv;
                    gv = fminf(gv, 7.f);
                    uv = fminf(fmaxf(uv, -7.f), 7.f);
                    float glu = gv / (1.f + __expf(-1.702f * gv));
                    act[(size_t)grow * IDIM + col] = f2bf((uv + 1.f) * glu);
                }
            }
        }
    }
}

// =====================================================================
// grouped GEMM 2: outs = act @ w_down + b_down
// BM=256, BN=256, BK=64, 512 thr / 8 waves (2m x 4n), wave tile 128x64.
// Same counted-vmcnt split-MFMA pipeline.
// =====================================================================
__global__ __launch_bounds__(512, 2) void gemm2_kernel(
    const unsigned short* __restrict__ actb, const float* __restrict__ w_down,
    const float* __restrict__ b_down, const int* __restrict__ tile_e,
    const int* __restrict__ tile_r, const int* __restrict__ ntiles,
    const int* __restrict__ offsets, const int* __restrict__ counts,
    unsigned short* __restrict__ outs)
{
    int flat = blockIdx.y * 8 + blockIdx.x;
    int swz = (flat & 7) * (MAXT) + (flat >> 3);
    int tid = swz >> 3, nb = swz & 7;
    if (tid >= ntiles[0]) return;
    int e = tile_e[tid], row0 = tile_r[tid];
    int cnt_end = offsets[e] + counts[e];
    int n0 = nb * 256;

    __shared__ unsigned short As[2][BM * 64];   // 64 KB
    __shared__ unsigned short Bs[2][256 * 64];  // 64 KB

    int t = threadIdx.x, lane = t & 63, w = t >> 6;
    int wr = w >> 2, wc = w & 3;
    int lrow = lane & 15, lg8 = (lane >> 4) * 8;

    f32x4 acc[8][4];
#pragma unroll
    for (int m = 0; m < 8; m++)
#pragma unroll
        for (int n = 0; n < 4; n++) acc[m][n] = (f32x4)0.f;

    int arow_l = (lane >> 3);
    int achunk = (lane & 7) ^ arow_l;
    int bn = (t & 63) * 4, bk = w * 8;
    int bfswz = (lane & 7) << 3;
    size_t wB = (size_t)e * ((size_t)IDIM * HDIM) + (size_t)bk * HDIM + n0 + bn;

    f32x4 dS0[8], dS1[8];

#define G2_STAGE_A(KT, BUF) do { int k0_ = (KT) * 64; \
    _Pragma("unroll") for (int i_ = 0; i_ < 4; i_++) { \
        int ar_ = row0 + 32 * w + 8 * i_ + arow_l; \
        if (ar_ > TKROW - 1) ar_ = TKROW - 1; \
        gload16(actb + (size_t)ar_ * IDIM + k0_ + achunk * 8, \
                (void*)&As[BUF][(32 * w + 8 * i_) * 64]); \
    } } while (0)

#define G2_LOADB(KT, DV) do { \
    const float* gp_ = w_down + wB + (size_t)(KT) * 64 * HDIM; \
    _Pragma("unroll") for (int kk_ = 0; kk_ < 8; kk_++) \
        DV[kk_] = *(const f32x4*)(gp_ + (size_t)kk_ * HDIM); \
    } while (0)

#define G2_WRITEB(DV, BUF) do { \
    _Pragma("unroll") for (int j_ = 0; j_ < 4; j_++) { \
        uint4 v_; \
        v_.x = cvtpkp(DV[0][j_], DV[1][j_]); v_.y = cvtpkp(DV[2][j_], DV[3][j_]); \
        v_.z = cvtpkp(DV[4][j_], DV[5][j_]); v_.w = cvtpkp(DV[6][j_], DV[7][j_]); \
        int d_ = (bn + j_) * 64 + (bk ^ bfswz); \
        *(uint4*)&Bs[BUF][d_] = v_; \
    } } while (0)

#define G2_MFMA_H(BUF, KK) do { \
    __builtin_amdgcn_s_setprio(1); \
    { \
        short8 af_[8], bf_[4]; \
        int ke_ = (KK) * 32 + lg8; \
        _Pragma("unroll") for (int m_ = 0; m_ < 8; m_++) \
            af_[m_] = *(const short8*)&As[BUF][(wr * 128 + m_ * 16 + lrow) * 64 + (ke_ ^ ((lrow & 7) << 3))]; \
        _Pragma("unroll") for (int n_ = 0; n_ < 4; n_++) { \
            int rb_ = wc * 64 + n_ * 16 + lrow; \
            bf_[n_] = *(const short8*)&Bs[BUF][rb_ * 64 + (ke_ ^ (((rb_ >> 2) & 7) << 3))]; \
        } \
        _Pragma("unroll") for (int m_ = 0; m_ < 8; m_++) \
        _Pragma("unroll") for (int n_ = 0; n_ < 4; n_++) \
            acc[m_][n_] = mfma16(af_[m_], bf_[n_], acc[m_][n_]); \
    } \
    __builtin_amdgcn_s_setprio(0); } while (0)

    G2_STAGE_A(0, 0); FENCE();
    G2_LOADB(0, dS0); FENCE();
    G2_LOADB(1, dS1); FENCE();
    WAITVM(8);
    G2_WRITEB(dS0, 0);
    LGKM0(); BAR();

    int cur = 0;
#pragma unroll 1
    for (int kt = 0; kt < 14; kt += 2) {
        FENCE(); G2_STAGE_A(kt + 1, cur ^ 1); FENCE();
        G2_LOADB(kt + 2, dS0); FENCE();
        G2_MFMA_H(cur, 0);
        WAITVM(12);
        G2_WRITEB(dS1, cur ^ 1);
        G2_MFMA_H(cur, 1);
        WAITVM(8);
        LGKM0(); BAR(); cur ^= 1;
        FENCE(); G2_STAGE_A(kt + 2, cur ^ 1); FENCE();
        G2_LOADB(kt + 3, dS1); FENCE();
        G2_MFMA_H(cur, 0);
        WAITVM(12);
        G2_WRITEB(dS0, cur ^ 1);
        G2_MFMA_H(cur, 1);
        WAITVM(8);
        LGKM0(); BAR(); cur ^= 1;
    }
    // t=14
    FENCE(); G2_STAGE_A(15, cur ^ 1); FENCE();
    G2_MFMA_H(cur, 0);
    WAITVM(4);
    G2_WRITEB(dS1, cur ^ 1);
    G2_MFMA_H(cur, 1);
    WAITVM(0);
    LGKM0(); BAR(); cur ^= 1;
    // t=15
    G2_MFMA_H(cur, 0);
    G2_MFMA_H(cur, 1);
#undef G2_STAGE_A
#undef G2_LOADB
#undef G2_WRITEB
#undef G2_MFMA_H

#pragma unroll
    for (int nf = 0; nf < 4; nf++) {
        int col = n0 + wc * 64 + nf * 16 + lrow;
        float bdv = b_down[e * HDIM + col];
#pragma unroll
        for (int m = 0; m < 8; m++) {
            int rb = row0 + wr * 128 + m * 16 + (lane >> 4) * 4;
#pragma unroll
            for (int r = 0; r < 4; r++) {
                int grow = rb + r;
                if (grow < cnt_end)
                    outs[(size_t)grow * HDIM + col] = f2bf(acc[m][nf][r] + bdv);
            }
        }
    }
}

// ---------------- combine ----------------
__global__ __launch_bounds__(256) void combine_kernel(
    const unsigned short* __restrict__ outs, const int* __restrict__ pos_of,
    const float* __restrict__ topk_w, float* __restrict__ y)
{
    int tok = blockIdx.x;
    int c0 = threadIdx.x * 8;
    float acc[8] = {0.f, 0.f, 0.f, 0.f, 0.f, 0.f, 0.f, 0.f};
#pragma unroll
    for (int k = 0; k < 4; k++) {
        int pos = pos_of[tok * 4 + k];
        float w = topk_w[tok * 4 + k];
        short8 vv = *(const short8*)(outs + (size_t)pos * HDIM + c0);
#pragma unroll
        for (int j = 0; j < 8; j++)
            acc[j] = fmaf(w, bf2f((unsigned short)vv[j]), acc[j]);
    }
    float4 o0 = make_float4(acc[0], acc[1], acc[2], acc[3]);
    float4 o1 = make_float4(acc[4], acc[5], acc[6], acc[7]);
    *(float4*)(y + (size_t)tok * HDIM + c0)     = o0;
    *(float4*)(y + (size_t)tok * HDIM + c0 + 4) = o1;
}

// ---------------- launch ----------------
extern "C" void kernel_launch(void* const* d_in, const int* in_sizes, int n_in,
                              void* d_out, int out_size, void* d_ws, size_t ws_size,
                              hipStream_t stream) {
    const float* x      = (const float*)d_in[0];
    const float* gw     = (const float*)d_in[1];
    const float* gb     = (const float*)d_in[2];
    const float* w_gate = (const float*)d_in[3];
    const float* b_gate = (const float*)d_in[4];
    const float* w_up   = (const float*)d_in[5];
    const float* b_up   = (const float*)d_in[6];
    const float* w_down = (const float*)d_in[7];
    const float* b_down = (const float*)d_in[8];
    float* y = (float*)d_out;

    char* base = (char*)d_ws;
    size_t off = 0;
    int*   topk_idx = (int*)(base + off);   off += (size_t)TKROW * 4;
    float* topk_w   = (float*)(base + off); off += (size_t)TKROW * 4;
    int*   counts   = (int*)(base + off);   off += 256;
    int*   offsets  = (int*)(base + off);   off += 256;
    int*   fill     = (int*)(base + off);   off += 256;
    int*   ntiles   = (int*)(base + off);   off += 256;
    int*   tile_e   = (int*)(base + off);   off += 1024;
    int*   tile_r   = (int*)(base + off);   off += 1024;
    int*   pos_of   = (int*)(base + off);   off += (size_t)TKROW * 4;
    int*   row_tok  = (int*)(base + off);   off += (size_t)TKROW * 4;
    unsigned short* xt   = (unsigned short*)(base + off); off += (size_t)TKROW * HDIM * 2;
    unsigned short* act  = (unsigned short*)(base + off); off += (size_t)TKROW * IDIM * 2;
    unsigned short* outs = (unsigned short*)(base + off); off += (size_t)TKROW * HDIM * 2;

    init_kernel<<<1, 64, 0, stream>>>(counts, fill);
    gating_kernel<<<T_TOK / 4, 256, 0, stream>>>(x, gw, gb, topk_idx, topk_w);
    histo_kernel<<<TKROW / 256, 256, 0, stream>>>(topk_idx, counts);
    scan_tiles_kernel<<<1, 64, 0, stream>>>(counts, offsets, tile_e, tile_r, ntiles);
    scatter_kernel<<<TKROW / 256, 256, 0, stream>>>(topk_idx, offsets, fill, pos_of, row_tok);
    gather_kernel<<<TKROW, 64, 0, stream>>>(x, row_tok, xt);
    gemm1_kernel<<<dim3(8, MAXT), 512, 0, stream>>>(
        xt, w_gate, b_gate, w_up, b_up, tile_e, tile_r, ntiles, offsets, counts, act);
    gemm2_kernel<<<dim3(8, MAXT), 512, 0, stream>>>(
        act, w_down, b_down, tile_e, tile_r, ntiles, offsets, counts, outs);
    combine_kernel<<<T_TOK, 256, 0, stream>>>(outs, pos_of, topk_w, y);
}